// Round 2
// baseline (158.340 us; speedup 1.0000x reference)
//
#include <hip/hip_runtime.h>
#include <math.h>

// B=8, C=128, N=4096, d=16, groups=32
// R18 = R17 gnprep+qkv VERBATIM + attn occupancy-doubled.
//   R17 counters: attn 63us, MfmaUtil 27%, VALUBusy 40%, Occ 17.9% (=2
//   waves/SIMD, grid-limited), HBM 6%, conflicts ~0. 2360 cyc/tile vs ~640
//   cyc issue -> latency-bound, starved for waves.
//   Fix: 512-thr blocks (8 waves), K/V tile loop split by PARITY across wave
//   pairs (par = w>>2). Per-tile L2 traffic unchanged (same ihalf duplication),
//   waves/SIMD 2 -> 4 (VGPR 120 <= 128 budget). Epilogue: parity-combine
//   round via 72KB LDS overlay (2 blocks x 74.5KB <= 160KB/CU).
//   Chain cuts: v_permlane32_swap_b32 (VALU) replaces 4 ds_bpermute shfl +
//   16 selects; ls -> 4 partial sums; s_setprio around MFMA clusters (T5).
//   Predict attn 63 -> ~40us, Occ ~35%, MfmaUtil 40-50, VALUBusy 55-65.

typedef short v8s __attribute__((ext_vector_type(8)));   // 8 bf16 = 4 VGPRs
typedef float v16f __attribute__((ext_vector_type(16))); // 32x32 acc

__device__ __forceinline__ unsigned short f2bf_rne(float f) {
  unsigned u = __float_as_uint(f);
  u += 0x7fffu + ((u >> 16) & 1u);
  return (unsigned short)(u >> 16);
}

__device__ __forceinline__ v8s mk8(unsigned a, unsigned b, unsigned c, unsigned d) {
  union { unsigned u[4]; v8s s; } x;
  x.u[0] = a; x.u[1] = b; x.u[2] = c; x.u[3] = d;
  return x.s;
}

// pack two fp32 -> dword of 2 bf16 (truncation) in ONE v_perm_b32
__device__ __forceinline__ unsigned pack_trunc(float hi, float lo) {
  return __builtin_amdgcn_perm(__float_as_uint(hi), __float_as_uint(lo), 0x07060302u);
}

// tiled V element index: [b][j>>4][c][j&15]
#define VT(b, n, c) (((((size_t)(b) * 256 + ((n) >> 4)) << 7) + (c)) * 16 + ((n) & 15))

// ws byte offsets
#define WSB_MURS   0u
#define WSB_WCATB  4096u       // 160*128 bf16 = 40960
#define WSB_BCAT   49152u      // 160 f32
#define WSB_PWB    65536u      // 128*128 bf16 = 32768
#define WSB_QBF    131072u     // Q^T [B,16,N] bf16 = 1 MB
#define WSB_KBF    1310720u    // K [B,N,16] bf16 = 1 MB
#define WSB_VBF    2621440u    // 8 MB (tiled)

// ---------------------------------------------------------------------------
// gn_stats + prep fused. Grid 256 x 512 thr.  (VERBATIM)
// ---------------------------------------------------------------------------
__global__ __launch_bounds__(512)
void gnprep_kernel(const float* __restrict__ x, float* __restrict__ mu_rs,
                   const float* __restrict__ qw, const float* __restrict__ qb,
                   const float* __restrict__ kw, const float* __restrict__ kb,
                   const float* __restrict__ vw, const float* __restrict__ vb,
                   const float* __restrict__ pw,
                   unsigned short* __restrict__ wcatb, float* __restrict__ bcat,
                   unsigned short* __restrict__ pwb) {
  const int id = blockIdx.x;
  {
    const float qs = 0.36067376022224085f;  // 0.25 * log2(e)
    int idx = id * 512 + threadIdx.x;
    if (idx < 160 * 128) {
      int o = idx >> 7, c = idx & 127;
      float val;
      if (o < 16)       val = qw[o * 128 + c] * qs;
      else if (o < 32)  val = kw[(o - 16) * 128 + c];
      else              val = vw[(o - 32) * 128 + c];
      wcatb[idx] = f2bf_rne(val);
    } else if (idx < 160 * 128 + 160) {
      int o = idx - 160 * 128;
      bcat[o] = (o < 16) ? qb[o] * qs : (o < 32) ? kb[o - 16] : vb[o - 32];
    } else if (idx < 160 * 128 + 160 + 128 * 128) {
      int j = idx - (160 * 128 + 160);
      pwb[j] = f2bf_rne(pw[j]);
    }
  }
  const int bg = (id & 7) * 32 + (id >> 3);   // XCD swizzle: batch = id & 7
  const float4* xp = (const float4*)(x + (size_t)bg * 16384);
  float s = 0.f, ss = 0.f;
#pragma unroll
  for (int u = 0; u < 8; ++u) {
    int i = threadIdx.x + u * 512;
    float4 v = xp[i];
    s  += v.x + v.y + v.z + v.w;
    ss += v.x * v.x + v.y * v.y + v.z * v.z + v.w * v.w;
  }
  for (int off = 32; off > 0; off >>= 1) {
    s  += __shfl_down(s, off, 64);
    ss += __shfl_down(ss, off, 64);
  }
  __shared__ float red[16];
  int lane = threadIdx.x & 63, wid = threadIdx.x >> 6;
  if (lane == 0) { red[wid * 2] = s; red[wid * 2 + 1] = ss; }
  __syncthreads();
  if (threadIdx.x == 0) {
    float S = 0.f, SS = 0.f;
    for (int w = 0; w < 8; ++w) { S += red[w * 2]; SS += red[w * 2 + 1]; }
    float mu  = S * (1.0f / 16384.0f);
    float var = SS * (1.0f / 16384.0f) - mu * mu;
    float rs  = rsqrtf(var + 1e-5f);
    mu_rs[bg * 2]     = mu;
    mu_rs[bg * 2 + 1] = rs;
  }
}

// ---------------------------------------------------------------------------
// QKV: LDS-staged GEMM.  (VERBATIM)
// ---------------------------------------------------------------------------
#define HS 136   // shorts per hs row (128 data + 8 pad); 16B-aligned rows

__global__ __launch_bounds__(512)
void qkv_kernel(const float* __restrict__ x, const float* __restrict__ gnw,
                const float* __restrict__ gnb, const float* __restrict__ mu_rs,
                const unsigned short* __restrict__ wcatb, const float* __restrict__ bcat,
                unsigned short* __restrict__ qTb, unsigned short* __restrict__ kbf,
                unsigned short* __restrict__ vbf) {
  __shared__ alignas(16) unsigned short hs[64 * HS];   // 17408 B
  __shared__ float scsh[128], shsh[128], bsh[160];
  const int id = blockIdx.x;
  const int b = id & 7, nb = (id >> 3) << 6;   // XCD-pinned batch
  const int t = threadIdx.x;
  const int w = t >> 6, lane = t & 63, h = lane >> 5, l = lane & 31;
  const int nsub = w & 1, og = w >> 1;

  if (t < 128) {
    float mu = mu_rs[(b * 32 + (t >> 2)) * 2];
    float rs = mu_rs[(b * 32 + (t >> 2)) * 2 + 1];
    float gw = gnw[t], gb = gnb[t];
    scsh[t] = rs * gw; shsh[t] = gb - mu * rs * gw;
  }
  if (t < 160) bsh[t] = bcat[t];
  __syncthreads();

  // ---- stage: thread = (sn = t&63, c-quad base c00 = (t>>6)*4), 4 iters ----
  const int sn = t & 63;
  const int c00 = (t >> 6) * 4;
  const float* xb = x + ((size_t)b * 128 << 12) + nb + sn;
#pragma unroll
  for (int it = 0; it < 4; ++it) {
    const int c0 = c00 + it * 32;    // wave-uniform
    float f0 = xb[(size_t)(c0)     << 12] * scsh[c0]     + shsh[c0];
    float f1 = xb[(size_t)(c0 + 1) << 12] * scsh[c0 + 1] + shsh[c0 + 1];
    float f2 = xb[(size_t)(c0 + 2) << 12] * scsh[c0 + 2] + shsh[c0 + 2];
    float f3 = xb[(size_t)(c0 + 3) << 12] * scsh[c0 + 3] + shsh[c0 + 3];
    uint2 u;
    u.x = (unsigned)f2bf_rne(f0) | ((unsigned)f2bf_rne(f1) << 16);
    u.y = (unsigned)f2bf_rne(f2) | ((unsigned)f2bf_rne(f3) << 16);
    *(uint2*)(&hs[sn * HS + c0]) = u;
  }
  __syncthreads();

  // ---- MFMA: wave (nsub, og); og0 -> ot{0,1}, og1..3 -> ot{2..4} ----
  const int n = nb + nsub * 32 + l;
  const int otbase = (og == 0) ? 0 : og + 1;
  v16f acc[2];
#pragma unroll
  for (int a2 = 0; a2 < 2; ++a2)
#pragma unroll
    for (int r = 0; r < 16; ++r) acc[a2][r] = 0.f;

#pragma unroll
  for (int ks = 0; ks < 8; ++ks) {
    v8s bf = *(const v8s*)(&hs[(nsub * 32 + l) * HS + ks * 16 + 8 * h]);
    {
      v8s af = *(const v8s*)(wcatb + (otbase * 32 + l) * 128 + ks * 16 + 8 * h);
      acc[0] = __builtin_amdgcn_mfma_f32_32x32x16_bf16(af, bf, acc[0], 0, 0, 0);
    }
    if (og == 0) {
      v8s af = *(const v8s*)(wcatb + (32 + l) * 128 + ks * 16 + 8 * h);
      acc[1] = __builtin_amdgcn_mfma_f32_32x32x16_bf16(af, bf, acc[1], 0, 0, 0);
    }
  }

  // ---- epilogue (unchanged) ----
  if (og == 0) {
    const size_t nqk = ((size_t)b * 4096 + n) << 4;
#pragma unroll
    for (int r = 0; r < 16; ++r) {
      int o = 4 * h + (r & 3) + 8 * (r >> 2);
      unsigned short bv = f2bf_rne(acc[0][r] + bsh[o]);
      if (o < 16) qTb[((size_t)(b * 16 + o) << 12) + n] = bv;
      else        kbf[nqk + o - 16] = bv;
    }
#pragma unroll
    for (int r = 0; r < 16; ++r) {
      int o = 32 + 4 * h + (r & 3) + 8 * (r >> 2);
      vbf[VT(b, n, o - 32)] = f2bf_rne(acc[1][r] + bsh[o]);
    }
  } else {
#pragma unroll
    for (int r = 0; r < 16; ++r) {
      int o = otbase * 32 + 4 * h + (r & 3) + 8 * (r >> 2);
      vbf[VT(b, n, o - 32)] = f2bf_rne(acc[0][r] + bsh[o]);
    }
  }
}

// ---------------------------------------------------------------------------
// R18 flash attention + fused proj: 8 waves, tile-parity split, barrier-free
// main loop, V direct from L2, permlane32_swap exchange.
// Grid 512 x 512 thr. wave w: jsub = w&1, ihalf = (w>>1)&1, par = w>>2.
// ---------------------------------------------------------------------------
#define OTS 136                   // O^T row stride in shorts (68 dwords)
#define OVSL 4608                 // ov floats per combine slot (128 rows x 36)

__global__ __launch_bounds__(512)
void attn_kernel(const unsigned short* __restrict__ qTb,
                 const unsigned short* __restrict__ kbf,
                 const unsigned short* __restrict__ vbf,
                 const unsigned short* __restrict__ pwb,
                 const float* __restrict__ pb,
                 const float* __restrict__ x,
                 float* __restrict__ out) {
  // epilogue-only LDS: 4-slot f32 combine overlay, reused as O^T bf16
  __shared__ alignas(16) float ovs[4 * OVSL];   // 73728 B
  __shared__ float l_lds[64];
  __shared__ float pbs[128];

  const int id = blockIdx.x;
  const int b = id & 7, i0 = (id >> 3) << 6;   // XCD-pinned batch, 64-i tile
  const int t = threadIdx.x;
  const int w = t >> 6, lane = t & 63, h = lane >> 5, l = lane & 31;
  const int jsub = w & 1, ihalf = (w >> 1) & 1, par = w >> 2;

  // per-lane base pointers (fragment-coalesced: lane(h,l) at byte l*32+h*16)
  const unsigned short* kg = kbf + ((size_t)b << 16) + jsub * 512 + l * 16 + 8 * h;
  const unsigned short* vg = vbf + ((size_t)b << 19) + jsub * 4096 + l * 16 + 8 * h;

  if (t < 128) pbs[t] = pb[t];
  if (t < 64) l_lds[t] = 0.f;

  // Q B-frag from Q^T [B,16,N]: 8 coalesced b16 loads, once per kernel
  const int iglob = i0 + ihalf * 32 + l;
  unsigned qd[4];
#pragma unroll
  for (int e = 0; e < 4; ++e) {
    unsigned lo = qTb[((size_t)(b * 16 + 8 * h + 2 * e) << 12) + iglob];
    unsigned hi = qTb[((size_t)(b * 16 + 8 * h + 2 * e + 1) << 12) + iglob];
    qd[e] = lo | (hi << 16);
  }
  const v8s qf = mk8(qd[0], qd[1], qd[2], qd[3]);

  v16f zc;
#pragma unroll
  for (int r = 0; r < 16; ++r) zc[r] = 0.f;
  v16f acc[4];
#pragma unroll
  for (int ct = 0; ct < 4; ++ct)
#pragma unroll
    for (int r = 0; r < 16; ++r) acc[ct][r] = 0.f;
  float ls0 = 0.f, ls1 = 0.f, ls2 = 0.f, ls3 = 0.f;

  __syncthreads();   // l_lds zeros visible before any epilogue atomicAdd

  // prologue: own-parity tile-0 K frag + 8 V frags into regs
  v8s kf = *(const v8s*)(kg + (size_t)par * 1024);
  v8s vf[8];
  {
    const unsigned short* vp = vg + (size_t)par * 8192;
#pragma unroll
    for (int ct = 0; ct < 4; ++ct) {
      vf[2 * ct]     = *(const v8s*)(vp + ct * 512);
      vf[2 * ct + 1] = *(const v8s*)(vp + 2048 + ct * 512);
    }
  }

#pragma unroll 2
  for (int tile = par; tile < 64; tile += 2) {
    const int tn = (tile + 2) & 63;   // wrap: harmless reload on last iter

    // issue next-tile loads FIRST; latency hidden under QK + softmax + PV
    v8s kn = *(const v8s*)(kg + (size_t)tn * 1024);
    v8s vn[8];
    const unsigned short* vt = vg + (size_t)tn * 8192;
#pragma unroll
    for (int ct = 0; ct < 4; ++ct) {
      vn[2 * ct]     = *(const v8s*)(vt + ct * 512);
      vn[2 * ct + 1] = *(const v8s*)(vt + 2048 + ct * 512);
    }

    // QK: S^T patch (rows j, cols i) -> P in regs
    __builtin_amdgcn_s_setprio(1);
    v16f st = __builtin_amdgcn_mfma_f32_32x32x16_bf16(kf, qf, zc, 0, 0, 0);
    __builtin_amdgcn_s_setprio(0);
    float pe[16];
#pragma unroll
    for (int r = 0; r < 16; ++r) pe[r] = __builtin_amdgcn_exp2f(st[r]);
    ls0 += pe[0] + pe[4] + pe[8]  + pe[12];
    ls1 += pe[1] + pe[5] + pe[9]  + pe[13];
    ls2 += pe[2] + pe[6] + pe[10] + pe[14];
    ls3 += pe[3] + pe[7] + pe[11] + pe[15];
    unsigned G[8];
#pragma unroll
    for (int g = 0; g < 4; ++g) {
      G[2 * g]     = pack_trunc(pe[4 * g + 1], pe[4 * g]);
      G[2 * g + 1] = pack_trunc(pe[4 * g + 3], pe[4 * g + 2]);
    }
    // half-wave exchange via v_permlane32_swap_b32 (pure VALU, no LDS pipe):
    // swap(a,b): a' = {a.lo, b.lo}, b' = {a.hi, b.hi}
    unsigned A0 = G[0], B0 = G[2], A1 = G[1], B1 = G[3];
    unsigned A2 = G[4], B2 = G[6], A3 = G[5], B3 = G[7];
    asm("v_permlane32_swap_b32 %0, %1" : "+v"(A0), "+v"(B0));
    asm("v_permlane32_swap_b32 %0, %1" : "+v"(A1), "+v"(B1));
    asm("v_permlane32_swap_b32 %0, %1" : "+v"(A2), "+v"(B2));
    asm("v_permlane32_swap_b32 %0, %1" : "+v"(A3), "+v"(B3));
    v8s pf0 = mk8(A0, A1, B0, B1);
    v8s pf1 = mk8(A2, A3, B2, B3);

    // PV on current-tile register fragments (no LDS, no barrier)
    __builtin_amdgcn_s_setprio(1);
#pragma unroll
    for (int ct = 0; ct < 4; ++ct) {
      acc[ct] = __builtin_amdgcn_mfma_f32_32x32x16_bf16(vf[2 * ct],     pf0, acc[ct], 0, 0, 0);
      acc[ct] = __builtin_amdgcn_mfma_f32_32x32x16_bf16(vf[2 * ct + 1], pf1, acc[ct], 0, 0, 0);
    }
    __builtin_amdgcn_s_setprio(0);

    // rotate prefetch (copies vanish under unroll-2 renaming)
    kf = kn;
#pragma unroll
    for (int u = 0; u < 8; ++u) vf[u] = vn[u];
  }

  // ---- epilogue: parity combine, jsub combine, then fused proj ----
  atomicAdd(&l_lds[ihalf * 32 + l], (ls0 + ls1) + (ls2 + ls3));

  float* const ov = ovs;
  // stage A: par=1 waves write acc to slot (jsub*2+ihalf)
  if (par == 1) {
    const int s = (jsub * 2 + ihalf) * OVSL;
#pragma unroll
    for (int ct = 0; ct < 4; ++ct)
#pragma unroll
      for (int q = 0; q < 4; ++q) {
        float4 v4 = {acc[ct][4 * q], acc[ct][4 * q + 1],
                     acc[ct][4 * q + 2], acc[ct][4 * q + 3]};
        *(float4*)&ov[s + (ct * 32 + l) * 36 + 4 * h + 8 * q] = v4;
      }
  }
  __syncthreads();
  if (par == 0) {
    const int s = (jsub * 2 + ihalf) * OVSL;
#pragma unroll
    for (int ct = 0; ct < 4; ++ct)
#pragma unroll
      for (int q = 0; q < 4; ++q) {
        float4 v4 = *(float4*)&ov[s + (ct * 32 + l) * 36 + 4 * h + 8 * q];
        acc[ct][4 * q]     += v4.x;
        acc[ct][4 * q + 1] += v4.y;
        acc[ct][4 * q + 2] += v4.z;
        acc[ct][4 * q + 3] += v4.w;
      }
  }
  __syncthreads();
  // stage B: jsub combine among par=0 waves (slots 0/1 reused)
  if (par == 0 && jsub == 1) {
    const int s = ihalf * OVSL;
#pragma unroll
    for (int ct = 0; ct < 4; ++ct)
#pragma unroll
      for (int q = 0; q < 4; ++q) {
        float4 v4 = {acc[ct][4 * q], acc[ct][4 * q + 1],
                     acc[ct][4 * q + 2], acc[ct][4 * q + 3]};
        *(float4*)&ov[s + (ct * 32 + l) * 36 + 4 * h + 8 * q] = v4;
      }
  }
  __syncthreads();
  if (par == 0 && jsub == 0) {
    const int s = ihalf * OVSL;
#pragma unroll
    for (int ct = 0; ct < 4; ++ct)
#pragma unroll
      for (int q = 0; q < 4; ++q) {
        float4 v4 = *(float4*)&ov[s + (ct * 32 + l) * 36 + 4 * h + 8 * q];
        acc[ct][4 * q]     += v4.x;
        acc[ct][4 * q + 1] += v4.y;
        acc[ct][4 * q + 2] += v4.z;
        acc[ct][4 * q + 3] += v4.w;
      }
  }
  __syncthreads();   // slot reads complete; overlay reusable as O^T

  // par=0,jsub=0 waves write normalized O^T bf16 [n_local][c], stride OTS
  unsigned short* const oT = (unsigned short*)ovs;
  if (par == 0 && jsub == 0) {
    const float li = 1.f / l_lds[ihalf * 32 + l];
    const int nrow = ihalf * 32 + l;
#pragma unroll
    for (int ct = 0; ct < 4; ++ct)
#pragma unroll
      for (int r = 0; r < 16; r += 2) {
        int c = ct * 32 + 4 * h + (r & 3) + 8 * (r >> 2);   // even
        unsigned dw = (unsigned)f2bf_rne(acc[ct][r] * li) |
                      ((unsigned)f2bf_rne(acc[ct][r + 1] * li) << 16);
        *(unsigned*)(&oT[nrow * OTS + c]) = dw;
      }
  }
  __syncthreads();

  // fused proj: wave w -> (e-tile w>>1, nsub w&1). out = pw@O + pb + x.
  {
    const int eg = w >> 1, nsub = w & 1;
    v16f a2;
#pragma unroll
    for (int r = 0; r < 16; ++r) a2[r] = 0.f;
#pragma unroll
    for (int ks = 0; ks < 8; ++ks) {
      v8s bf = *(const v8s*)(&oT[(nsub * 32 + l) * OTS + ks * 16 + 8 * h]);
      v8s af = *(const v8s*)(pwb + (eg * 32 + l) * 128 + ks * 16 + 8 * h);
      a2 = __builtin_amdgcn_mfma_f32_32x32x16_bf16(af, bf, a2, 0, 0, 0);
    }
    const int n = i0 + nsub * 32 + l;
#pragma unroll
    for (int r = 0; r < 16; ++r) {
      int e = eg * 32 + 4 * h + (r & 3) + 8 * (r >> 2);
      size_t idx = ((size_t)(b * 128 + e) << 12) + n;
      out[idx] = a2[r] + pbs[e] + x[idx];
    }
  }
}

// ---------------------------------------------------------------------------
extern "C" void kernel_launch(void* const* d_in, const int* in_sizes, int n_in,
                              void* d_out, int out_size, void* d_ws, size_t ws_size,
                              hipStream_t stream) {
  const float* x   = (const float*)d_in[0];
  const float* gnw = (const float*)d_in[1];
  const float* gnb = (const float*)d_in[2];
  const float* qw  = (const float*)d_in[3];
  const float* qb  = (const float*)d_in[4];
  const float* kw  = (const float*)d_in[5];
  const float* kb  = (const float*)d_in[6];
  const float* vw  = (const float*)d_in[7];
  const float* vb  = (const float*)d_in[8];
  const float* pw  = (const float*)d_in[9];
  const float* pb  = (const float*)d_in[10];
  float* out = (float*)d_out;
  char* ws = (char*)d_ws;

  float* mu_rs = (float*)(ws + WSB_MURS);
  unsigned short* wcatb = (unsigned short*)(ws + WSB_WCATB);
  float* bcat = (float*)(ws + WSB_BCAT);
  unsigned short* pwb = (unsigned short*)(ws + WSB_PWB);
  unsigned short* qTb = (unsigned short*)(ws + WSB_QBF);
  unsigned short* kbf = (unsigned short*)(ws + WSB_KBF);
  unsigned short* vbf = (unsigned short*)(ws + WSB_VBF);

  hipLaunchKernelGGL(gnprep_kernel, dim3(256), dim3(512), 0, stream,
                     x, mu_rs, qw, qb, kw, kb, vw, vb, pw, wcatb, bcat, pwb);
  hipLaunchKernelGGL(qkv_kernel, dim3(512), dim3(512), 0, stream,
                     x, gnw, gnb, mu_rs, wcatb, bcat, qTb, kbf, vbf);
  hipLaunchKernelGGL(attn_kernel, dim3(512), dim3(512), 0, stream,
                     qTb, kbf, vbf, pwb, pb, x, out);
}

// Round 4
// 155.235 us; speedup vs baseline: 1.0200x; 1.0200x over previous
//
#include <hip/hip_runtime.h>
#include <math.h>

// B=8, C=128, N=4096, d=16, groups=32
// R20 = R19 with the compile fix: no LDS-pointer array (gfx950 rejects the
//   addrspacecast static initializer); buffer base computed from (tile&1).
//   Theory unchanged: R17 attn (63us) is ~half L2-BW-bound (V read twice per
//   block by ihalf wave pairs: 4.6MB/CU ~= 34us floor) + half chain-latency.
//   Stage V tile (16KB contiguous in VT layout) ONCE per block via
//   global_load_lds (async DMA, no VGPR round-trip), double-buffered,
//   1 barrier/tile -> per-CU L2 traffic 2.6MB. PV frags = contiguous
//   1KB/wave ds_read_b128 (conflict-free). K reg-prefetched. Softmax
//   (permlane32_swap, 4-partial ls) + epilogue proven, unchanged.
//   Predict attn 63 -> 42-52us, VGPR ~115, conflicts <0.5M, LDS 38KB.

typedef short v8s __attribute__((ext_vector_type(8)));   // 8 bf16 = 4 VGPRs
typedef float v16f __attribute__((ext_vector_type(16))); // 32x32 acc

__device__ __forceinline__ unsigned short f2bf_rne(float f) {
  unsigned u = __float_as_uint(f);
  u += 0x7fffu + ((u >> 16) & 1u);
  return (unsigned short)(u >> 16);
}

__device__ __forceinline__ v8s mk8(unsigned a, unsigned b, unsigned c, unsigned d) {
  union { unsigned u[4]; v8s s; } x;
  x.u[0] = a; x.u[1] = b; x.u[2] = c; x.u[3] = d;
  return x.s;
}

// pack two fp32 -> dword of 2 bf16 (truncation) in ONE v_perm_b32
__device__ __forceinline__ unsigned pack_trunc(float hi, float lo) {
  return __builtin_amdgcn_perm(__float_as_uint(hi), __float_as_uint(lo), 0x07060302u);
}

// async 16B global -> LDS (DMA). LDS dest = uniform base + lane*16 (HW adds).
__device__ __forceinline__ void gl_lds16(const void* g, void* l) {
  __builtin_amdgcn_global_load_lds(
      (const __attribute__((address_space(1))) unsigned int*)g,
      (__attribute__((address_space(3))) unsigned int*)l, 16, 0, 0);
}

// tiled V element index: [b][j>>4][c][j&15]
#define VT(b, n, c) (((((size_t)(b) * 256 + ((n) >> 4)) << 7) + (c)) * 16 + ((n) & 15))

// ws byte offsets
#define WSB_MURS   0u
#define WSB_WCATB  4096u       // 160*128 bf16 = 40960
#define WSB_BCAT   49152u      // 160 f32
#define WSB_PWB    65536u      // 128*128 bf16 = 32768
#define WSB_QBF    131072u     // Q^T [B,16,N] bf16 = 1 MB
#define WSB_KBF    1310720u    // K [B,N,16] bf16 = 1 MB
#define WSB_VBF    2621440u    // 8 MB (tiled)

// ---------------------------------------------------------------------------
// gn_stats + prep fused. Grid 256 x 512 thr.  (VERBATIM)
// ---------------------------------------------------------------------------
__global__ __launch_bounds__(512)
void gnprep_kernel(const float* __restrict__ x, float* __restrict__ mu_rs,
                   const float* __restrict__ qw, const float* __restrict__ qb,
                   const float* __restrict__ kw, const float* __restrict__ kb,
                   const float* __restrict__ vw, const float* __restrict__ vb,
                   const float* __restrict__ pw,
                   unsigned short* __restrict__ wcatb, float* __restrict__ bcat,
                   unsigned short* __restrict__ pwb) {
  const int id = blockIdx.x;
  {
    const float qs = 0.36067376022224085f;  // 0.25 * log2(e)
    int idx = id * 512 + threadIdx.x;
    if (idx < 160 * 128) {
      int o = idx >> 7, c = idx & 127;
      float val;
      if (o < 16)       val = qw[o * 128 + c] * qs;
      else if (o < 32)  val = kw[(o - 16) * 128 + c];
      else              val = vw[(o - 32) * 128 + c];
      wcatb[idx] = f2bf_rne(val);
    } else if (idx < 160 * 128 + 160) {
      int o = idx - 160 * 128;
      bcat[o] = (o < 16) ? qb[o] * qs : (o < 32) ? kb[o - 16] : vb[o - 32];
    } else if (idx < 160 * 128 + 160 + 128 * 128) {
      int j = idx - (160 * 128 + 160);
      pwb[j] = f2bf_rne(pw[j]);
    }
  }
  const int bg = (id & 7) * 32 + (id >> 3);   // XCD swizzle: batch = id & 7
  const float4* xp = (const float4*)(x + (size_t)bg * 16384);
  float s = 0.f, ss = 0.f;
#pragma unroll
  for (int u = 0; u < 8; ++u) {
    int i = threadIdx.x + u * 512;
    float4 v = xp[i];
    s  += v.x + v.y + v.z + v.w;
    ss += v.x * v.x + v.y * v.y + v.z * v.z + v.w * v.w;
  }
  for (int off = 32; off > 0; off >>= 1) {
    s  += __shfl_down(s, off, 64);
    ss += __shfl_down(ss, off, 64);
  }
  __shared__ float red[16];
  int lane = threadIdx.x & 63, wid = threadIdx.x >> 6;
  if (lane == 0) { red[wid * 2] = s; red[wid * 2 + 1] = ss; }
  __syncthreads();
  if (threadIdx.x == 0) {
    float S = 0.f, SS = 0.f;
    for (int w = 0; w < 8; ++w) { S += red[w * 2]; SS += red[w * 2 + 1]; }
    float mu  = S * (1.0f / 16384.0f);
    float var = SS * (1.0f / 16384.0f) - mu * mu;
    float rs  = rsqrtf(var + 1e-5f);
    mu_rs[bg * 2]     = mu;
    mu_rs[bg * 2 + 1] = rs;
  }
}

// ---------------------------------------------------------------------------
// QKV: LDS-staged GEMM.  (VERBATIM)
// ---------------------------------------------------------------------------
#define HS 136   // shorts per hs row (128 data + 8 pad); 16B-aligned rows

__global__ __launch_bounds__(512)
void qkv_kernel(const float* __restrict__ x, const float* __restrict__ gnw,
                const float* __restrict__ gnb, const float* __restrict__ mu_rs,
                const unsigned short* __restrict__ wcatb, const float* __restrict__ bcat,
                unsigned short* __restrict__ qTb, unsigned short* __restrict__ kbf,
                unsigned short* __restrict__ vbf) {
  __shared__ alignas(16) unsigned short hs[64 * HS];   // 17408 B
  __shared__ float scsh[128], shsh[128], bsh[160];
  const int id = blockIdx.x;
  const int b = id & 7, nb = (id >> 3) << 6;   // XCD-pinned batch
  const int t = threadIdx.x;
  const int w = t >> 6, lane = t & 63, h = lane >> 5, l = lane & 31;
  const int nsub = w & 1, og = w >> 1;

  if (t < 128) {
    float mu = mu_rs[(b * 32 + (t >> 2)) * 2];
    float rs = mu_rs[(b * 32 + (t >> 2)) * 2 + 1];
    float gw = gnw[t], gb = gnb[t];
    scsh[t] = rs * gw; shsh[t] = gb - mu * rs * gw;
  }
  if (t < 160) bsh[t] = bcat[t];
  __syncthreads();

  // ---- stage: thread = (sn = t&63, c-quad base c00 = (t>>6)*4), 4 iters ----
  const int sn = t & 63;
  const int c00 = (t >> 6) * 4;
  const float* xb = x + ((size_t)b * 128 << 12) + nb + sn;
#pragma unroll
  for (int it = 0; it < 4; ++it) {
    const int c0 = c00 + it * 32;    // wave-uniform
    float f0 = xb[(size_t)(c0)     << 12] * scsh[c0]     + shsh[c0];
    float f1 = xb[(size_t)(c0 + 1) << 12] * scsh[c0 + 1] + shsh[c0 + 1];
    float f2 = xb[(size_t)(c0 + 2) << 12] * scsh[c0 + 2] + shsh[c0 + 2];
    float f3 = xb[(size_t)(c0 + 3) << 12] * scsh[c0 + 3] + shsh[c0 + 3];
    uint2 u;
    u.x = (unsigned)f2bf_rne(f0) | ((unsigned)f2bf_rne(f1) << 16);
    u.y = (unsigned)f2bf_rne(f2) | ((unsigned)f2bf_rne(f3) << 16);
    *(uint2*)(&hs[sn * HS + c0]) = u;
  }
  __syncthreads();

  // ---- MFMA: wave (nsub, og); og0 -> ot{0,1}, og1..3 -> ot{2..4} ----
  const int n = nb + nsub * 32 + l;
  const int otbase = (og == 0) ? 0 : og + 1;
  v16f acc[2];
#pragma unroll
  for (int a2 = 0; a2 < 2; ++a2)
#pragma unroll
    for (int r = 0; r < 16; ++r) acc[a2][r] = 0.f;

#pragma unroll
  for (int ks = 0; ks < 8; ++ks) {
    v8s bf = *(const v8s*)(&hs[(nsub * 32 + l) * HS + ks * 16 + 8 * h]);
    {
      v8s af = *(const v8s*)(wcatb + (otbase * 32 + l) * 128 + ks * 16 + 8 * h);
      acc[0] = __builtin_amdgcn_mfma_f32_32x32x16_bf16(af, bf, acc[0], 0, 0, 0);
    }
    if (og == 0) {
      v8s af = *(const v8s*)(wcatb + (32 + l) * 128 + ks * 16 + 8 * h);
      acc[1] = __builtin_amdgcn_mfma_f32_32x32x16_bf16(af, bf, acc[1], 0, 0, 0);
    }
  }

  // ---- epilogue (unchanged) ----
  if (og == 0) {
    const size_t nqk = ((size_t)b * 4096 + n) << 4;
#pragma unroll
    for (int r = 0; r < 16; ++r) {
      int o = 4 * h + (r & 3) + 8 * (r >> 2);
      unsigned short bv = f2bf_rne(acc[0][r] + bsh[o]);
      if (o < 16) qTb[((size_t)(b * 16 + o) << 12) + n] = bv;
      else        kbf[nqk + o - 16] = bv;
    }
#pragma unroll
    for (int r = 0; r < 16; ++r) {
      int o = 32 + 4 * h + (r & 3) + 8 * (r >> 2);
      vbf[VT(b, n, o - 32)] = f2bf_rne(acc[1][r] + bsh[o]);
    }
  } else {
#pragma unroll
    for (int r = 0; r < 16; ++r) {
      int o = otbase * 32 + 4 * h + (r & 3) + 8 * (r >> 2);
      vbf[VT(b, n, o - 32)] = f2bf_rne(acc[0][r] + bsh[o]);
    }
  }
}

// ---------------------------------------------------------------------------
// R20 flash attention + fused proj: 4 waves (jsub, ihalf); V staged to LDS
// via global_load_lds double-buffer, 1 barrier/tile; PV frags contiguous
// 1KB/wave ds_read_b128. Grid 512 x 256 thr.
// ---------------------------------------------------------------------------
#define OTS 136                   // O^T row stride in shorts (68 dwords)

__global__ __launch_bounds__(256)
void attn_kernel(const unsigned short* __restrict__ qTb,
                 const unsigned short* __restrict__ kbf,
                 const unsigned short* __restrict__ vbf,
                 const unsigned short* __restrict__ pwb,
                 const float* __restrict__ pb,
                 const float* __restrict__ x,
                 float* __restrict__ out) {
  // main loop: V double-buffer 2x16KB; epilogue overlays same region
  __shared__ alignas(16) unsigned char smem[36864];
  __shared__ float l_lds[64];
  __shared__ float pbs[128];

  const int id = blockIdx.x;
  const int b = id & 7, i0 = (id >> 3) << 6;   // XCD-pinned batch, 64-i tile
  const int t = threadIdx.x;
  const int w = t >> 6, lane = t & 63, h = lane >> 5, l = lane & 31;
  const int jsub = w & 1, ihalf = w >> 1;

  // per-lane K base (fragment-coalesced: lane(h,l) at byte l*32+h*16)
  const unsigned short* kg = kbf + ((size_t)b << 16) + jsub * 512 + l * 16 + 8 * h;
  const unsigned short* vgb = vbf + ((size_t)b << 19);   // batch V base (shorts)

  if (t < 128) pbs[t] = pb[t];
  if (t < 64) l_lds[t] = 0.f;

  // Q B-frag from Q^T [B,16,N]: 8 coalesced b16 loads, once per kernel
  const int iglob = i0 + ihalf * 32 + l;
  unsigned qd[4];
#pragma unroll
  for (int e = 0; e < 4; ++e) {
    unsigned lo = qTb[((size_t)(b * 16 + 8 * h + 2 * e) << 12) + iglob];
    unsigned hi = qTb[((size_t)(b * 16 + 8 * h + 2 * e + 1) << 12) + iglob];
    qd[e] = lo | (hi << 16);
  }
  const v8s qf = mk8(qd[0], qd[1], qd[2], qd[3]);

  v16f zc;
#pragma unroll
  for (int r = 0; r < 16; ++r) zc[r] = 0.f;
  v16f acc[4];
#pragma unroll
  for (int ct = 0; ct < 4; ++ct)
#pragma unroll
    for (int r = 0; r < 16; ++r) acc[ct][r] = 0.f;
  float ls0 = 0.f, ls1 = 0.f, ls2 = 0.f, ls3 = 0.f;

  // prologue: stage tile 0 into buf0 (16 chunks of 1KB; wave w -> qi*4+w)
#pragma unroll
  for (int qi = 0; qi < 4; ++qi) {
    const int ch = qi * 4 + w;
    gl_lds16((const char*)vgb + ch * 1024 + lane * 16,
             (char*)smem + ch * 1024);
  }
  v8s kf = *(const v8s*)kg;   // tile 0 K frag
  __syncthreads();            // compiler drains vmcnt+lgkmcnt before barrier

  for (int tile = 0; tile < 64; ++tile) {
    unsigned short* const cur = (unsigned short*)(smem + (size_t)(tile & 1) * 16384);
    char* const nxt = (char*)smem + (size_t)((tile + 1) & 1) * 16384;
    const int tn = (tile + 1) & 63;   // wrap: harmless reload on last iter

    // stage next V tile (async DMA into nxt; consumed after tail barrier)
    const char* vt = (const char*)vgb + (size_t)tn * 16384;
#pragma unroll
    for (int qi = 0; qi < 4; ++qi) {
      const int ch = qi * 4 + w;
      gl_lds16(vt + ch * 1024 + lane * 16, nxt + ch * 1024);
    }
    // prefetch next K frag
    v8s kn = *(const v8s*)(kg + (size_t)tn * 1024);

    // QK: S^T patch (rows j, cols i) -> P in regs
    v16f st = __builtin_amdgcn_mfma_f32_32x32x16_bf16(kf, qf, zc, 0, 0, 0);
    float pe[16];
#pragma unroll
    for (int r = 0; r < 16; ++r) pe[r] = __builtin_amdgcn_exp2f(st[r]);
    ls0 += pe[0] + pe[4] + pe[8]  + pe[12];
    ls1 += pe[1] + pe[5] + pe[9]  + pe[13];
    ls2 += pe[2] + pe[6] + pe[10] + pe[14];
    ls3 += pe[3] + pe[7] + pe[11] + pe[15];
    unsigned G[8];
#pragma unroll
    for (int g = 0; g < 4; ++g) {
      G[2 * g]     = pack_trunc(pe[4 * g + 1], pe[4 * g]);
      G[2 * g + 1] = pack_trunc(pe[4 * g + 3], pe[4 * g + 2]);
    }
    // half-wave exchange via v_permlane32_swap_b32 (pure VALU; proven R18)
    unsigned A0 = G[0], B0 = G[2], A1 = G[1], B1 = G[3];
    unsigned A2 = G[4], B2 = G[6], A3 = G[5], B3 = G[7];
    asm("v_permlane32_swap_b32 %0, %1" : "+v"(A0), "+v"(B0));
    asm("v_permlane32_swap_b32 %0, %1" : "+v"(A1), "+v"(B1));
    asm("v_permlane32_swap_b32 %0, %1" : "+v"(A2), "+v"(B2));
    asm("v_permlane32_swap_b32 %0, %1" : "+v"(A3), "+v"(B3));
    v8s pf0 = mk8(A0, A1, B0, B1);
    v8s pf1 = mk8(A2, A3, B2, B3);

    // PV: contiguous per-wave 1KB ds_read_b128 frags from cur
    const unsigned short* vj = cur + jsub * 4096 + l * 16 + 8 * h;
    __builtin_amdgcn_s_setprio(1);
#pragma unroll
    for (int ct = 0; ct < 4; ++ct) {
      v8s vf0 = *(const v8s*)(vj + ct * 512);
      v8s vf1 = *(const v8s*)(vj + 2048 + ct * 512);
      acc[ct] = __builtin_amdgcn_mfma_f32_32x32x16_bf16(vf0, pf0, acc[ct], 0, 0, 0);
      acc[ct] = __builtin_amdgcn_mfma_f32_32x32x16_bf16(vf1, pf1, acc[ct], 0, 0, 0);
    }
    __builtin_amdgcn_s_setprio(0);

    kf = kn;
    __syncthreads();   // stage(nxt) drained + all reads of cur done
  }

  // ---- epilogue: jsub combine, then fused proj (R17 logic verbatim) ----
  atomicAdd(&l_lds[ihalf * 32 + l], (ls0 + ls1) + (ls2 + ls3));
  __syncthreads();   // all PV reads done; V buffers dead; l complete

  float* const ov = (float*)smem;   // f32 combine overlay
  if (jsub == 1) {
#pragma unroll
    for (int ct = 0; ct < 4; ++ct)
#pragma unroll
      for (int q = 0; q < 4; ++q) {
        float4 v4 = {acc[ct][4 * q], acc[ct][4 * q + 1],
                     acc[ct][4 * q + 2], acc[ct][4 * q + 3]};
        *(float4*)&ov[((ct * 2 + ihalf) * 32 + l) * 36 + 4 * h + 8 * q] = v4;
      }
  }
  __syncthreads();
  if (jsub == 0) {
#pragma unroll
    for (int ct = 0; ct < 4; ++ct)
#pragma unroll
      for (int q = 0; q < 4; ++q) {
        float4 v4 = *(float4*)&ov[((ct * 2 + ihalf) * 32 + l) * 36 + 4 * h + 8 * q];
        acc[ct][4 * q]     += v4.x;
        acc[ct][4 * q + 1] += v4.y;
        acc[ct][4 * q + 2] += v4.z;
        acc[ct][4 * q + 3] += v4.w;
      }
  }
  __syncthreads();   // ov reads complete; smem reusable

  // jsub=0 waves write normalized O^T bf16 [n_local][c], stride OTS
  unsigned short* const oT = (unsigned short*)smem;
  if (jsub == 0) {
    const float li = 1.f / l_lds[ihalf * 32 + l];
    const int nrow = ihalf * 32 + l;
#pragma unroll
    for (int ct = 0; ct < 4; ++ct)
#pragma unroll
      for (int r = 0; r < 16; r += 2) {
        int c = ct * 32 + 4 * h + (r & 3) + 8 * (r >> 2);   // even
        unsigned dw = (unsigned)f2bf_rne(acc[ct][r] * li) |
                      ((unsigned)f2bf_rne(acc[ct][r + 1] * li) << 16);
        *(unsigned*)(&oT[nrow * OTS + c]) = dw;
      }
  }
  __syncthreads();

  // fused proj: wave w -> e-tile w (32 e), both n-subs. out = pw@O + pb + x.
#pragma unroll
  for (int nsub = 0; nsub < 2; ++nsub) {
    v16f a2;
#pragma unroll
    for (int r = 0; r < 16; ++r) a2[r] = 0.f;
#pragma unroll
    for (int ks = 0; ks < 8; ++ks) {
      v8s bf = *(const v8s*)(&oT[(nsub * 32 + l) * OTS + ks * 16 + 8 * h]);
      v8s af = *(const v8s*)(pwb + (w * 32 + l) * 128 + ks * 16 + 8 * h);
      a2 = __builtin_amdgcn_mfma_f32_32x32x16_bf16(af, bf, a2, 0, 0, 0);
    }
    const int n = i0 + nsub * 32 + l;
#pragma unroll
    for (int r = 0; r < 16; ++r) {
      int e = w * 32 + 4 * h + (r & 3) + 8 * (r >> 2);
      size_t idx = ((size_t)(b * 128 + e) << 12) + n;
      out[idx] = a2[r] + pbs[e] + x[idx];
    }
  }
}

// ---------------------------------------------------------------------------
extern "C" void kernel_launch(void* const* d_in, const int* in_sizes, int n_in,
                              void* d_out, int out_size, void* d_ws, size_t ws_size,
                              hipStream_t stream) {
  const float* x   = (const float*)d_in[0];
  const float* gnw = (const float*)d_in[1];
  const float* gnb = (const float*)d_in[2];
  const float* qw  = (const float*)d_in[3];
  const float* qb  = (const float*)d_in[4];
  const float* kw  = (const float*)d_in[5];
  const float* kb  = (const float*)d_in[6];
  const float* vw  = (const float*)d_in[7];
  const float* vb  = (const float*)d_in[8];
  const float* pw  = (const float*)d_in[9];
  const float* pb  = (const float*)d_in[10];
  float* out = (float*)d_out;
  char* ws = (char*)d_ws;

  float* mu_rs = (float*)(ws + WSB_MURS);
  unsigned short* wcatb = (unsigned short*)(ws + WSB_WCATB);
  float* bcat = (float*)(ws + WSB_BCAT);
  unsigned short* pwb = (unsigned short*)(ws + WSB_PWB);
  unsigned short* qTb = (unsigned short*)(ws + WSB_QBF);
  unsigned short* kbf = (unsigned short*)(ws + WSB_KBF);
  unsigned short* vbf = (unsigned short*)(ws + WSB_VBF);

  hipLaunchKernelGGL(gnprep_kernel, dim3(256), dim3(512), 0, stream,
                     x, mu_rs, qw, qb, kw, kb, vw, vb, pw, wcatb, bcat, pwb);
  hipLaunchKernelGGL(qkv_kernel, dim3(512), dim3(512), 0, stream,
                     x, gnw, gnb, mu_rs, wcatb, bcat, qTb, kbf, vbf);
  hipLaunchKernelGGL(attn_kernel, dim3(512), dim3(256), 0, stream,
                     qTb, kbf, vbf, pwb, pb, x, out);
}

// Round 5
// 153.278 us; speedup vs baseline: 1.0330x; 1.0128x over previous
//
#include <hip/hip_runtime.h>
#include <math.h>

// B=8, C=128, N=4096, d=16, groups=32
// R21 = gnprep+qkv VERBATIM + attn = R17 (best, 63us) with prefetch depth
//   1 -> 2 via 3-buffer register rotation.
//   Evidence: R16(LDS+barrier)=71, R17(reg,depth1)=63, R20(LDS DMA+barrier)
//   =69.5 with conflicts back at 4.3M (lane l*32+h*16 pattern = 4-way/phase)
//   and the vmcnt(0) barrier drain. Structure, not V L2 volume, sets time.
//   R17 is latency-bound: ~31 B/cy/CU from L2 (>50% of share) -> queuing
//   inflates load latency past one tile-body; depth-1 prefetch too shallow.
//   Occupancy is GRID-limited (512 blk x 4 waves = 2 waves/SIMD), so VGPR
//   for 3 V buffers (96 regs) is free. launch_bounds(256,1) lifts the cap.
//   Rotation: BODY(t, use, load): issue V(t+2)/K(t+2) -> load-buf, then
//   QK/softmax/PV on use-buf. 21 x {(A,C),(B,A),(C,B)} + tail(63) -> all
//   buffer names static, copies vanish, no runtime indexing (no scratch).
//   Predict: VGPR 190-240 (diagnostic; <=140 => pipeline collapsed), attn
//   63 -> 46-56us, MfmaUtil 30-38, VALUBusy 50-62, conflicts ~65K.

typedef short v8s __attribute__((ext_vector_type(8)));   // 8 bf16 = 4 VGPRs
typedef float v16f __attribute__((ext_vector_type(16))); // 32x32 acc

__device__ __forceinline__ unsigned short f2bf_rne(float f) {
  unsigned u = __float_as_uint(f);
  u += 0x7fffu + ((u >> 16) & 1u);
  return (unsigned short)(u >> 16);
}

__device__ __forceinline__ v8s mk8(unsigned a, unsigned b, unsigned c, unsigned d) {
  union { unsigned u[4]; v8s s; } x;
  x.u[0] = a; x.u[1] = b; x.u[2] = c; x.u[3] = d;
  return x.s;
}

// pack two fp32 -> dword of 2 bf16 (truncation) in ONE v_perm_b32
__device__ __forceinline__ unsigned pack_trunc(float hi, float lo) {
  return __builtin_amdgcn_perm(__float_as_uint(hi), __float_as_uint(lo), 0x07060302u);
}

// tiled V element index: [b][j>>4][c][j&15]
#define VT(b, n, c) (((((size_t)(b) * 256 + ((n) >> 4)) << 7) + (c)) * 16 + ((n) & 15))

// ws byte offsets
#define WSB_MURS   0u
#define WSB_WCATB  4096u       // 160*128 bf16 = 40960
#define WSB_BCAT   49152u      // 160 f32
#define WSB_PWB    65536u      // 128*128 bf16 = 32768
#define WSB_QBF    131072u     // Q^T [B,16,N] bf16 = 1 MB
#define WSB_KBF    1310720u    // K [B,N,16] bf16 = 1 MB
#define WSB_VBF    2621440u    // 8 MB (tiled)

// ---------------------------------------------------------------------------
// gn_stats + prep fused. Grid 256 x 512 thr.  (VERBATIM)
// ---------------------------------------------------------------------------
__global__ __launch_bounds__(512)
void gnprep_kernel(const float* __restrict__ x, float* __restrict__ mu_rs,
                   const float* __restrict__ qw, const float* __restrict__ qb,
                   const float* __restrict__ kw, const float* __restrict__ kb,
                   const float* __restrict__ vw, const float* __restrict__ vb,
                   const float* __restrict__ pw,
                   unsigned short* __restrict__ wcatb, float* __restrict__ bcat,
                   unsigned short* __restrict__ pwb) {
  const int id = blockIdx.x;
  {
    const float qs = 0.36067376022224085f;  // 0.25 * log2(e)
    int idx = id * 512 + threadIdx.x;
    if (idx < 160 * 128) {
      int o = idx >> 7, c = idx & 127;
      float val;
      if (o < 16)       val = qw[o * 128 + c] * qs;
      else if (o < 32)  val = kw[(o - 16) * 128 + c];
      else              val = vw[(o - 32) * 128 + c];
      wcatb[idx] = f2bf_rne(val);
    } else if (idx < 160 * 128 + 160) {
      int o = idx - 160 * 128;
      bcat[o] = (o < 16) ? qb[o] * qs : (o < 32) ? kb[o - 16] : vb[o - 32];
    } else if (idx < 160 * 128 + 160 + 128 * 128) {
      int j = idx - (160 * 128 + 160);
      pwb[j] = f2bf_rne(pw[j]);
    }
  }
  const int bg = (id & 7) * 32 + (id >> 3);   // XCD swizzle: batch = id & 7
  const float4* xp = (const float4*)(x + (size_t)bg * 16384);
  float s = 0.f, ss = 0.f;
#pragma unroll
  for (int u = 0; u < 8; ++u) {
    int i = threadIdx.x + u * 512;
    float4 v = xp[i];
    s  += v.x + v.y + v.z + v.w;
    ss += v.x * v.x + v.y * v.y + v.z * v.z + v.w * v.w;
  }
  for (int off = 32; off > 0; off >>= 1) {
    s  += __shfl_down(s, off, 64);
    ss += __shfl_down(ss, off, 64);
  }
  __shared__ float red[16];
  int lane = threadIdx.x & 63, wid = threadIdx.x >> 6;
  if (lane == 0) { red[wid * 2] = s; red[wid * 2 + 1] = ss; }
  __syncthreads();
  if (threadIdx.x == 0) {
    float S = 0.f, SS = 0.f;
    for (int w = 0; w < 8; ++w) { S += red[w * 2]; SS += red[w * 2 + 1]; }
    float mu  = S * (1.0f / 16384.0f);
    float var = SS * (1.0f / 16384.0f) - mu * mu;
    float rs  = rsqrtf(var + 1e-5f);
    mu_rs[bg * 2]     = mu;
    mu_rs[bg * 2 + 1] = rs;
  }
}

// ---------------------------------------------------------------------------
// QKV: LDS-staged GEMM.  (VERBATIM)
// ---------------------------------------------------------------------------
#define HS 136   // shorts per hs row (128 data + 8 pad); 16B-aligned rows

__global__ __launch_bounds__(512)
void qkv_kernel(const float* __restrict__ x, const float* __restrict__ gnw,
                const float* __restrict__ gnb, const float* __restrict__ mu_rs,
                const unsigned short* __restrict__ wcatb, const float* __restrict__ bcat,
                unsigned short* __restrict__ qTb, unsigned short* __restrict__ kbf,
                unsigned short* __restrict__ vbf) {
  __shared__ alignas(16) unsigned short hs[64 * HS];   // 17408 B
  __shared__ float scsh[128], shsh[128], bsh[160];
  const int id = blockIdx.x;
  const int b = id & 7, nb = (id >> 3) << 6;   // XCD-pinned batch
  const int t = threadIdx.x;
  const int w = t >> 6, lane = t & 63, h = lane >> 5, l = lane & 31;
  const int nsub = w & 1, og = w >> 1;

  if (t < 128) {
    float mu = mu_rs[(b * 32 + (t >> 2)) * 2];
    float rs = mu_rs[(b * 32 + (t >> 2)) * 2 + 1];
    float gw = gnw[t], gb = gnb[t];
    scsh[t] = rs * gw; shsh[t] = gb - mu * rs * gw;
  }
  if (t < 160) bsh[t] = bcat[t];
  __syncthreads();

  // ---- stage: thread = (sn = t&63, c-quad base c00 = (t>>6)*4), 4 iters ----
  const int sn = t & 63;
  const int c00 = (t >> 6) * 4;
  const float* xb = x + ((size_t)b * 128 << 12) + nb + sn;
#pragma unroll
  for (int it = 0; it < 4; ++it) {
    const int c0 = c00 + it * 32;    // wave-uniform
    float f0 = xb[(size_t)(c0)     << 12] * scsh[c0]     + shsh[c0];
    float f1 = xb[(size_t)(c0 + 1) << 12] * scsh[c0 + 1] + shsh[c0 + 1];
    float f2 = xb[(size_t)(c0 + 2) << 12] * scsh[c0 + 2] + shsh[c0 + 2];
    float f3 = xb[(size_t)(c0 + 3) << 12] * scsh[c0 + 3] + shsh[c0 + 3];
    uint2 u;
    u.x = (unsigned)f2bf_rne(f0) | ((unsigned)f2bf_rne(f1) << 16);
    u.y = (unsigned)f2bf_rne(f2) | ((unsigned)f2bf_rne(f3) << 16);
    *(uint2*)(&hs[sn * HS + c0]) = u;
  }
  __syncthreads();

  // ---- MFMA: wave (nsub, og); og0 -> ot{0,1}, og1..3 -> ot{2..4} ----
  const int n = nb + nsub * 32 + l;
  const int otbase = (og == 0) ? 0 : og + 1;
  v16f acc[2];
#pragma unroll
  for (int a2 = 0; a2 < 2; ++a2)
#pragma unroll
    for (int r = 0; r < 16; ++r) acc[a2][r] = 0.f;

#pragma unroll
  for (int ks = 0; ks < 8; ++ks) {
    v8s bf = *(const v8s*)(&hs[(nsub * 32 + l) * HS + ks * 16 + 8 * h]);
    {
      v8s af = *(const v8s*)(wcatb + (otbase * 32 + l) * 128 + ks * 16 + 8 * h);
      acc[0] = __builtin_amdgcn_mfma_f32_32x32x16_bf16(af, bf, acc[0], 0, 0, 0);
    }
    if (og == 0) {
      v8s af = *(const v8s*)(wcatb + (32 + l) * 128 + ks * 16 + 8 * h);
      acc[1] = __builtin_amdgcn_mfma_f32_32x32x16_bf16(af, bf, acc[1], 0, 0, 0);
    }
  }

  // ---- epilogue (unchanged) ----
  if (og == 0) {
    const size_t nqk = ((size_t)b * 4096 + n) << 4;
#pragma unroll
    for (int r = 0; r < 16; ++r) {
      int o = 4 * h + (r & 3) + 8 * (r >> 2);
      unsigned short bv = f2bf_rne(acc[0][r] + bsh[o]);
      if (o < 16) qTb[((size_t)(b * 16 + o) << 12) + n] = bv;
      else        kbf[nqk + o - 16] = bv;
    }
#pragma unroll
    for (int r = 0; r < 16; ++r) {
      int o = 32 + 4 * h + (r & 3) + 8 * (r >> 2);
      vbf[VT(b, n, o - 32)] = f2bf_rne(acc[1][r] + bsh[o]);
    }
  } else {
#pragma unroll
    for (int r = 0; r < 16; ++r) {
      int o = otbase * 32 + 4 * h + (r & 3) + 8 * (r >> 2);
      vbf[VT(b, n, o - 32)] = f2bf_rne(acc[0][r] + bsh[o]);
    }
  }
}

// ---------------------------------------------------------------------------
// R21 flash attention + fused proj: R17 structure (4 waves, barrier-free,
// V/K direct from L2) with 3-buffer depth-2 register pipeline.
// Grid 512 x 256 thr. wave w: jsub = w&1, ihalf = w>>1.
// ---------------------------------------------------------------------------
#define OTS 136                   // O^T row stride in shorts (68 dwords)

// issue V(T+2) -> VL[8], K(T+2) -> KL  (wrap harmless)
#define STAGE(T, VL, KL) {                                        \
  const int tn_ = ((T) + 2) & 63;                                 \
  const unsigned short* vt_ = vg + (size_t)tn_ * 8192;            \
  _Pragma("unroll") for (int ct = 0; ct < 4; ++ct) {              \
    VL[2 * ct]     = *(const v8s*)(vt_ + ct * 512);               \
    VL[2 * ct + 1] = *(const v8s*)(vt_ + 2048 + ct * 512);        \
  }                                                               \
  KL = *(const v8s*)(kg + (size_t)tn_ * 1024);                    \
}

// QK -> exp2 -> pack -> permlane exchange -> PV, on use-buffers VU/KU
#define COMPUTE(VU, KU) {                                                   \
  v16f st = __builtin_amdgcn_mfma_f32_32x32x16_bf16(KU, qf, zc, 0, 0, 0);   \
  float pe[16];                                                             \
  _Pragma("unroll") for (int r = 0; r < 16; ++r)                            \
    pe[r] = __builtin_amdgcn_exp2f(st[r]);                                  \
  ls0 += pe[0] + pe[4] + pe[8]  + pe[12];                                   \
  ls1 += pe[1] + pe[5] + pe[9]  + pe[13];                                   \
  ls2 += pe[2] + pe[6] + pe[10] + pe[14];                                   \
  ls3 += pe[3] + pe[7] + pe[11] + pe[15];                                   \
  unsigned G[8];                                                            \
  _Pragma("unroll") for (int g = 0; g < 4; ++g) {                           \
    G[2 * g]     = pack_trunc(pe[4 * g + 1], pe[4 * g]);                    \
    G[2 * g + 1] = pack_trunc(pe[4 * g + 3], pe[4 * g + 2]);                \
  }                                                                         \
  unsigned A0 = G[0], B0 = G[2], A1 = G[1], B1 = G[3];                      \
  unsigned A2 = G[4], B2 = G[6], A3 = G[5], B3 = G[7];                      \
  asm("v_permlane32_swap_b32 %0, %1" : "+v"(A0), "+v"(B0));                 \
  asm("v_permlane32_swap_b32 %0, %1" : "+v"(A1), "+v"(B1));                 \
  asm("v_permlane32_swap_b32 %0, %1" : "+v"(A2), "+v"(B2));                 \
  asm("v_permlane32_swap_b32 %0, %1" : "+v"(A3), "+v"(B3));                 \
  v8s pf0 = mk8(A0, A1, B0, B1);                                            \
  v8s pf1 = mk8(A2, A3, B2, B3);                                            \
  __builtin_amdgcn_s_setprio(1);                                            \
  _Pragma("unroll") for (int ct = 0; ct < 4; ++ct) {                        \
    acc[ct] = __builtin_amdgcn_mfma_f32_32x32x16_bf16(VU[2 * ct],     pf0,  \
                                                      acc[ct], 0, 0, 0);    \
    acc[ct] = __builtin_amdgcn_mfma_f32_32x32x16_bf16(VU[2 * ct + 1], pf1,  \
                                                      acc[ct], 0, 0, 0);    \
  }                                                                         \
  __builtin_amdgcn_s_setprio(0);                                            \
}

__global__ __launch_bounds__(256, 1)
void attn_kernel(const unsigned short* __restrict__ qTb,
                 const unsigned short* __restrict__ kbf,
                 const unsigned short* __restrict__ vbf,
                 const unsigned short* __restrict__ pwb,
                 const float* __restrict__ pb,
                 const float* __restrict__ x,
                 float* __restrict__ out) {
  // epilogue-only LDS: f32 combine overlay (36864 B) reused as O^T bf16
  __shared__ alignas(16) float ovs[9216];
  __shared__ float l_lds[64];
  __shared__ float pbs[128];

  const int id = blockIdx.x;
  const int b = id & 7, i0 = (id >> 3) << 6;   // XCD-pinned batch, 64-i tile
  const int t = threadIdx.x;
  const int w = t >> 6, lane = t & 63, h = lane >> 5, l = lane & 31;
  const int jsub = w & 1, ihalf = w >> 1;

  // per-lane base pointers (fragment-coalesced: lane(h,l) at byte l*32+h*16)
  const unsigned short* kg = kbf + ((size_t)b << 16) + jsub * 512 + l * 16 + 8 * h;
  const unsigned short* vg = vbf + ((size_t)b << 19) + jsub * 4096 + l * 16 + 8 * h;

  if (t < 128) pbs[t] = pb[t];
  if (t < 64) l_lds[t] = 0.f;

  // Q B-frag from Q^T [B,16,N]: 8 coalesced b16 loads, once per kernel
  const int iglob = i0 + ihalf * 32 + l;
  unsigned qd[4];
#pragma unroll
  for (int e = 0; e < 4; ++e) {
    unsigned lo = qTb[((size_t)(b * 16 + 8 * h + 2 * e) << 12) + iglob];
    unsigned hi = qTb[((size_t)(b * 16 + 8 * h + 2 * e + 1) << 12) + iglob];
    qd[e] = lo | (hi << 16);
  }
  const v8s qf = mk8(qd[0], qd[1], qd[2], qd[3]);

  v16f zc;
#pragma unroll
  for (int r = 0; r < 16; ++r) zc[r] = 0.f;
  v16f acc[4];
#pragma unroll
  for (int ct = 0; ct < 4; ++ct)
#pragma unroll
    for (int r = 0; r < 16; ++r) acc[ct][r] = 0.f;
  float ls0 = 0.f, ls1 = 0.f, ls2 = 0.f, ls3 = 0.f;

  __syncthreads();   // l_lds zeros visible before any epilogue atomicAdd

  // prologue: V(0)->va, V(1)->vb, K(0)->ka, K(1)->kb
  v8s va[8], vb[8], vc[8], ka, kb, kc;
#pragma unroll
  for (int ct = 0; ct < 4; ++ct) {
    va[2 * ct]     = *(const v8s*)(vg + ct * 512);
    va[2 * ct + 1] = *(const v8s*)(vg + 2048 + ct * 512);
  }
#pragma unroll
  for (int ct = 0; ct < 4; ++ct) {
    vb[2 * ct]     = *(const v8s*)(vg + 8192 + ct * 512);
    vb[2 * ct + 1] = *(const v8s*)(vg + 8192 + 2048 + ct * 512);
  }
  ka = *(const v8s*)kg;
  kb = *(const v8s*)(kg + 1024);

  // 3-buffer rotation, distance-2 prefetch: 21 x 3 bodies + tail (tile 63).
  // BODY(T, use, load): STAGE issues V(T+2)/K(T+2) into load-buf (free since
  // T-1's compute), then COMPUTE consumes use-buf (issued 2 bodies ago).
  for (int i = 0; i < 21; ++i) {
    const int t3 = 3 * i;
    { STAGE(t3,     vc, kc); COMPUTE(va, ka); }
    { STAGE(t3 + 1, va, ka); COMPUTE(vb, kb); }
    { STAGE(t3 + 2, vb, kb); COMPUTE(vc, kc); }
  }
  { STAGE(63, vc, kc); COMPUTE(va, ka); }   // tail: va=V(63), ka=K(63)

  // ---- epilogue: jsub combine, then fused proj (R17 logic verbatim) ----
  atomicAdd(&l_lds[ihalf * 32 + l], (ls0 + ls1) + (ls2 + ls3));
  __syncthreads();   // l complete; ovs free

  float* const ov = ovs;   // f32 combine overlay
  if (jsub == 1) {
#pragma unroll
    for (int ct = 0; ct < 4; ++ct)
#pragma unroll
      for (int q = 0; q < 4; ++q) {
        float4 v4 = {acc[ct][4 * q], acc[ct][4 * q + 1],
                     acc[ct][4 * q + 2], acc[ct][4 * q + 3]};
        *(float4*)&ov[((ct * 2 + ihalf) * 32 + l) * 36 + 4 * h + 8 * q] = v4;
      }
  }
  __syncthreads();
  if (jsub == 0) {
#pragma unroll
    for (int ct = 0; ct < 4; ++ct)
#pragma unroll
      for (int q = 0; q < 4; ++q) {
        float4 v4 = *(float4*)&ov[((ct * 2 + ihalf) * 32 + l) * 36 + 4 * h + 8 * q];
        acc[ct][4 * q]     += v4.x;
        acc[ct][4 * q + 1] += v4.y;
        acc[ct][4 * q + 2] += v4.z;
        acc[ct][4 * q + 3] += v4.w;
      }
  }
  __syncthreads();   // ov reads complete; overlay reusable

  // jsub=0 waves write normalized O^T bf16 [n_local][c], stride OTS
  unsigned short* const oT = (unsigned short*)ovs;
  if (jsub == 0) {
    const float li = 1.f / l_lds[ihalf * 32 + l];
    const int nrow = ihalf * 32 + l;
#pragma unroll
    for (int ct = 0; ct < 4; ++ct)
#pragma unroll
      for (int r = 0; r < 16; r += 2) {
        int c = ct * 32 + 4 * h + (r & 3) + 8 * (r >> 2);   // even
        unsigned dw = (unsigned)f2bf_rne(acc[ct][r] * li) |
                      ((unsigned)f2bf_rne(acc[ct][r + 1] * li) << 16);
        *(unsigned*)(&oT[nrow * OTS + c]) = dw;
      }
  }
  __syncthreads();

  // fused proj: wave w -> e-tile w (32 e), both n-subs. out = pw@O + pb + x.
#pragma unroll
  for (int nsub = 0; nsub < 2; ++nsub) {
    v16f a2;
#pragma unroll
    for (int r = 0; r < 16; ++r) a2[r] = 0.f;
#pragma unroll
    for (int ks = 0; ks < 8; ++ks) {
      v8s bf = *(const v8s*)(&oT[(nsub * 32 + l) * OTS + ks * 16 + 8 * h]);
      v8s af = *(const v8s*)(pwb + (w * 32 + l) * 128 + ks * 16 + 8 * h);
      a2 = __builtin_amdgcn_mfma_f32_32x32x16_bf16(af, bf, a2, 0, 0, 0);
    }
    const int n = i0 + nsub * 32 + l;
#pragma unroll
    for (int r = 0; r < 16; ++r) {
      int e = w * 32 + 4 * h + (r & 3) + 8 * (r >> 2);
      size_t idx = ((size_t)(b * 128 + e) << 12) + n;
      out[idx] = a2[r] + pbs[e] + x[idx];
    }
  }
}

// ---------------------------------------------------------------------------
extern "C" void kernel_launch(void* const* d_in, const int* in_sizes, int n_in,
                              void* d_out, int out_size, void* d_ws, size_t ws_size,
                              hipStream_t stream) {
  const float* x   = (const float*)d_in[0];
  const float* gnw = (const float*)d_in[1];
  const float* gnb = (const float*)d_in[2];
  const float* qw  = (const float*)d_in[3];
  const float* qb  = (const float*)d_in[4];
  const float* kw  = (const float*)d_in[5];
  const float* kb  = (const float*)d_in[6];
  const float* vw  = (const float*)d_in[7];
  const float* vb  = (const float*)d_in[8];
  const float* pw  = (const float*)d_in[9];
  const float* pb  = (const float*)d_in[10];
  float* out = (float*)d_out;
  char* ws = (char*)d_ws;

  float* mu_rs = (float*)(ws + WSB_MURS);
  unsigned short* wcatb = (unsigned short*)(ws + WSB_WCATB);
  float* bcat = (float*)(ws + WSB_BCAT);
  unsigned short* pwb = (unsigned short*)(ws + WSB_PWB);
  unsigned short* qTb = (unsigned short*)(ws + WSB_QBF);
  unsigned short* kbf = (unsigned short*)(ws + WSB_KBF);
  unsigned short* vbf = (unsigned short*)(ws + WSB_VBF);

  hipLaunchKernelGGL(gnprep_kernel, dim3(256), dim3(512), 0, stream,
                     x, mu_rs, qw, qb, kw, kb, vw, vb, pw, wcatb, bcat, pwb);
  hipLaunchKernelGGL(qkv_kernel, dim3(512), dim3(512), 0, stream,
                     x, gnw, gnb, mu_rs, wcatb, bcat, qTb, kbf, vbf);
  hipLaunchKernelGGL(attn_kernel, dim3(512), dim3(256), 0, stream,
                     qTb, kbf, vbf, pwb, pb, x, out);
}